// Round 9
// baseline (718.268 us; speedup 1.0000x reference)
//
#include <hip/hip_runtime.h>
#include <hip/hip_bf16.h>

#define D_DIM 128
#define AST 136   // padded LDS row stride (shorts) for the A' tile (136 = 8*17)

typedef __attribute__((ext_vector_type(8))) short short8v;
typedef __attribute__((ext_vector_type(4))) short short4v;
typedef __attribute__((ext_vector_type(4))) float floatx4;

__device__ __forceinline__ short f2bf(float x) {
    unsigned u = __builtin_bit_cast(unsigned, x);
    unsigned r = u + 0x7fff + ((u >> 16) & 1);   // RNE
    return (short)(r >> 16);
}
__device__ __forceinline__ float bflo(unsigned p) {
    return __builtin_bit_cast(float, p << 16);
}
__device__ __forceinline__ float bfhi(unsigned p) {
    return __builtin_bit_cast(float, p & 0xffff0000u);
}

// ---------------- CSR build ----------------

__global__ void zero_cnt_kernel(int* __restrict__ cnt, int n) {
    int i = blockIdx.x * blockDim.x + threadIdx.x;
    if (i < n) cnt[i] = 0;
}

__global__ void count_kernel(const int* __restrict__ dst, int* __restrict__ cnt, int e) {
    int i = blockIdx.x * blockDim.x + threadIdx.x;
    if (i < e) atomicAdd(&cnt[dst[i]], 1);
}

__global__ __launch_bounds__(256) void partial_kernel(const int* __restrict__ cnt,
                                                      int* __restrict__ partial, int n) {
    const int b = blockIdx.x, t = threadIdx.x;
    const int base = b * 1024 + t * 4;
    int s = 0;
    if (base + 3 < n) {
        int4 c = *(const int4*)(cnt + base);
        s = c.x + c.y + c.z + c.w;
    } else {
        for (int j = 0; j < 4; ++j) if (base + j < n) s += cnt[base + j];
    }
    #pragma unroll
    for (int m = 1; m < 64; m <<= 1) s += __shfl_xor(s, m, 64);
    __shared__ int ws[4];
    if ((t & 63) == 0) ws[t >> 6] = s;
    __syncthreads();
    if (t == 0) partial[b] = ws[0] + ws[1] + ws[2] + ws[3];
}

__global__ __launch_bounds__(1024) void scan_partials_kernel(int* __restrict__ partial, int nb,
                                                             int* __restrict__ row_ptr,
                                                             int n, int e) {
    __shared__ int sh[1024];
    const int t = threadIdx.x;
    sh[t] = (t < nb) ? partial[t] : 0;
    __syncthreads();
    for (int off = 1; off < 1024; off <<= 1) {
        int v = (t >= off) ? sh[t - off] : 0;
        __syncthreads();
        sh[t] += v;
        __syncthreads();
    }
    if (t < nb) partial[t] = (t == 0) ? 0 : sh[t - 1];
    if (t == 0) row_ptr[n] = e;
}

__global__ __launch_bounds__(256) void emit_kernel(const int* __restrict__ cnt,
                                                   const int* __restrict__ partial,
                                                   int* __restrict__ row_ptr,
                                                   int* __restrict__ cursor,
                                                   float* __restrict__ dinv, int n) {
    const int b = blockIdx.x, t = threadIdx.x;
    const int base = b * 1024 + t * 4;
    int4 c = make_int4(0, 0, 0, 0);
    if (base + 3 < n) {
        c = *(const int4*)(cnt + base);
    } else {
        if (base     < n) c.x = cnt[base];
        if (base + 1 < n) c.y = cnt[base + 1];
        if (base + 2 < n) c.z = cnt[base + 2];
        if (base + 3 < n) c.w = cnt[base + 3];
    }
    const int ts = c.x + c.y + c.z + c.w;
    int incl = ts;
    const int lane = t & 63;
    #pragma unroll
    for (int off = 1; off < 64; off <<= 1) {
        int v = __shfl_up(incl, off, 64);
        if (lane >= off) incl += v;
    }
    __shared__ int wsum[4];
    if (lane == 63) wsum[t >> 6] = incl;
    __syncthreads();
    const int w = t >> 6;
    int waveoff = 0;
    #pragma unroll
    for (int i = 0; i < 3; ++i) if (i < w) waveoff += wsum[i];
    const int basev = partial[b] + waveoff + (incl - ts);
    const int e0 = basev, e1 = e0 + c.x, e2 = e1 + c.y, e3 = e2 + c.z;
    if (base + 3 < n) {
        *(int4*)(row_ptr + base) = make_int4(e0, e1, e2, e3);
        *(int4*)(cursor  + base) = make_int4(e0, e1, e2, e3);
        *(float4*)(dinv + base) = make_float4(rsqrtf((float)(c.x + 1)), rsqrtf((float)(c.y + 1)),
                                              rsqrtf((float)(c.z + 1)), rsqrtf((float)(c.w + 1)));
    } else {
        int es[4] = {e0, e1, e2, e3};
        int cs[4] = {c.x, c.y, c.z, c.w};
        for (int j = 0; j < 4; ++j) if (base + j < n) {
            row_ptr[base + j] = es[j];
            cursor[base + j]  = es[j];
            dinv[base + j]    = rsqrtf((float)(cs[j] + 1));
        }
    }
}

// fill CSR with precomputed per-edge weight: meta = {src, dinv[src]*dinv[dst]}
__global__ void fill_kernel(const int* __restrict__ src, const int* __restrict__ dst,
                            const float* __restrict__ dinv,
                            int* __restrict__ cursor, int2* __restrict__ meta, int e) {
    int i = blockIdx.x * blockDim.x + threadIdx.x;
    if (i < e) {
        int s = src[i], d = dst[i];
        int p = atomicAdd(&cursor[d], 1);
        float w = dinv[s] * dinv[d];
        meta[p] = make_int2(s, __builtin_bit_cast(int, w));
    }
}

// ---------------- W transpose+convert: Wt[l][n][k] = bf16(W[l][k][n]) ----------------
__global__ __launch_bounds__(256) void wt_prep_kernel(const float* __restrict__ W,
                                                      short* __restrict__ Wt, int total) {
    int o = blockIdx.x * blockDim.x + threadIdx.x;
    if (o >= total) return;
    int l = o >> 14;
    int r = o & 16383;
    int nn = r >> 7;
    int k  = r & 127;
    Wt[o] = f2bf(W[(size_t)l * 16384 + (size_t)k * 128 + nn]);
}

// ---------------- Fused layer: Y = LN(relu( (S·X) @ W + b )) ----------------
// Uses S·(X·W) = (S·X)·W. Block = 256 = 4 waves, 64 dst rows.
// Phase 1: wave wv gathers+aggregates dst rows [wv*16, wv*16+16) into bf16 A' tile (LDS).
// Phase 2: MFMA vs register-resident W (cols wv*32..+32), 32 MFMAs/wave.
// Phase 3: bias+relu, cross-wave LN stats via LDS ds_add_f32, normalize, store.
template <bool IN_F32, bool OUT_F32>
__global__ __launch_bounds__(256, 4) void fused_layer_kernel(const void* __restrict__ Xv,
                                                             const short* __restrict__ Wt,
                                                             const int* __restrict__ row_ptr,
                                                             const int2* __restrict__ meta,
                                                             const float* __restrict__ dinv,
                                                             const float* __restrict__ bias,
                                                             const float* __restrict__ gamma,
                                                             const float* __restrict__ beta,
                                                             void* __restrict__ Yv, int n) {
    __shared__ short Alds[64 * AST];     // aggregated A' tile, bf16
    __shared__ float Ps1[64 * 17];       // LN sum partials [row][m], pad 17
    __shared__ float Ps2[64 * 17];       // LN sumsq partials
    __shared__ float2 MuRs[64];

    const int t    = threadIdx.x;
    const int wv   = t >> 6;
    const int lane = t & 63;
    const int m    = lane & 15;
    const int quad = lane >> 4;
    const int row0 = blockIdx.x * 64;

    // zero LN partials (consumed after first barrier)
    for (int i = t; i < 64 * 17; i += 256) { Ps1[i] = 0.f; Ps2[i] = 0.f; }

    // B fragments (registers, loaded once; W is L2-resident)
    short8v bfr[2][4];
    #pragma unroll
    for (int c = 0; c < 2; ++c) {
        const short* bp = Wt + (size_t)((wv * 2 + c) * 16 + m) * D_DIM + quad * 8;
        #pragma unroll
        for (int kt = 0; kt < 4; ++kt)
            bfr[c][kt] = *(const short8v*)(bp + kt * 32);
    }

    // ---- Phase 1: gather-aggregate (wave-uniform v -> scalar metadata, SGPR weights)
    for (int rr = 0; rr < 16; ++rr) {
        const int v = row0 + wv * 16 + rr;
        float ax = 0.f, ay = 0.f;
        if (v < n) {
            const float dv = dinv[v];
            const int beg = row_ptr[v];
            const int end = row_ptr[v + 1];
            const float wself = dv * dv;
            if constexpr (IN_F32) {
                const float2 p = ((const float2*)((const float*)Xv + (size_t)v * D_DIM))[lane];
                ax = p.x * wself; ay = p.y * wself;
            } else {
                const unsigned p = ((const unsigned*)((const short*)Xv + (size_t)v * D_DIM))[lane];
                ax = bflo(p) * wself; ay = bfhi(p) * wself;
            }
            for (int i = beg; i < end; i += 8) {
                int   idx[8];
                float wgt[8];
                #pragma unroll
                for (int j = 0; j < 8; ++j) {
                    const int ii = min(i + j, end - 1);
                    const int2 mm = meta[ii];
                    idx[j] = mm.x;
                    wgt[j] = (i + j < end) ? __builtin_bit_cast(float, mm.y) : 0.f;
                }
                if constexpr (IN_F32) {
                    float2 p[8];
                    #pragma unroll
                    for (int j = 0; j < 8; ++j)
                        p[j] = ((const float2*)((const float*)Xv + (size_t)idx[j] * D_DIM))[lane];
                    #pragma unroll
                    for (int j = 0; j < 8; ++j) {
                        ax = fmaf(wgt[j], p[j].x, ax);
                        ay = fmaf(wgt[j], p[j].y, ay);
                    }
                } else {
                    unsigned p[8];
                    #pragma unroll
                    for (int j = 0; j < 8; ++j)
                        p[j] = ((const unsigned*)((const short*)Xv + (size_t)idx[j] * D_DIM))[lane];
                    #pragma unroll
                    for (int j = 0; j < 8; ++j) {
                        ax = fmaf(wgt[j], bflo(p[j]), ax);
                        ay = fmaf(wgt[j], bfhi(p[j]), ay);
                    }
                }
            }
        }
        const unsigned pk = (unsigned)(unsigned short)f2bf(ax) |
                            ((unsigned)(unsigned short)f2bf(ay) << 16);
        *(unsigned*)&Alds[(wv * 16 + rr) * AST + lane * 2] = pk;   // cols lane*2, lane*2+1
    }
    __syncthreads();

    // ---- Phase 2: MFMA
    floatx4 acc[4][2];
    #pragma unroll
    for (int rt = 0; rt < 4; ++rt) {
        const short* ab = &Alds[(rt * 16 + m) * AST + quad * 8];
        short8v afr[4];
        #pragma unroll
        for (int kt = 0; kt < 4; ++kt) afr[kt] = *(const short8v*)(ab + kt * 32);
        #pragma unroll
        for (int c = 0; c < 2; ++c) {
            floatx4 a = (floatx4){0.f, 0.f, 0.f, 0.f};
            #pragma unroll
            for (int kt = 0; kt < 4; ++kt)
                a = __builtin_amdgcn_mfma_f32_16x16x32_bf16(afr[kt], bfr[c][kt], a, 0, 0, 0);
            acc[rt][c] = a;
        }
    }

    // ---- Phase 3: bias + relu, LN stats (C/D: col=(wv*2+c)*16+m, row=rt*16+quad*4+r)
    const int col0 = wv * 32 + m;
    const int col1 = col0 + 16;
    const float b0 = bias[col0], b1 = bias[col1];
    #pragma unroll
    for (int rt = 0; rt < 4; ++rt) {
        #pragma unroll
        for (int r = 0; r < 4; ++r) {
            const float v0 = fmaxf(acc[rt][0][r] + b0, 0.f);
            const float v1 = fmaxf(acc[rt][1][r] + b1, 0.f);
            acc[rt][0][r] = v0;
            acc[rt][1][r] = v1;
            const int row = rt * 16 + quad * 4 + r;
            atomicAdd(&Ps1[row * 17 + m], v0 + v1);
            atomicAdd(&Ps2[row * 17 + m], v0 * v0 + v1 * v1);
        }
    }
    __syncthreads();

    // reduce 16 partials per row -> mu, rs
    {
        const int row = t >> 2;
        const int g = t & 3;
        float s1 = 0.f, s2 = 0.f;
        #pragma unroll
        for (int j = 0; j < 4; ++j) {
            s1 += Ps1[row * 17 + g * 4 + j];
            s2 += Ps2[row * 17 + g * 4 + j];
        }
        s1 += __shfl_xor(s1, 1, 64);  s2 += __shfl_xor(s2, 1, 64);
        s1 += __shfl_xor(s1, 2, 64);  s2 += __shfl_xor(s2, 2, 64);
        if (g == 0) {
            const float mu  = s1 * (1.f / 128.f);
            const float var = s2 * (1.f / 128.f) - mu * mu;
            MuRs[row] = make_float2(mu, rsqrtf(var + 1e-5f));
        }
    }
    __syncthreads();

    const float g0  = gamma[col0], g1  = gamma[col1];
    const float be0 = beta[col0],  be1 = beta[col1];
    #pragma unroll
    for (int rt = 0; rt < 4; ++rt) {
        #pragma unroll
        for (int r = 0; r < 4; ++r) {
            const int row  = rt * 16 + quad * 4 + r;
            const int grow = row0 + row;
            if (grow < n) {
                const float2 ms = MuRs[row];
                const float o0 = (acc[rt][0][r] - ms.x) * ms.y * g0 + be0;
                const float o1 = (acc[rt][1][r] - ms.x) * ms.y * g1 + be1;
                if constexpr (OUT_F32) {
                    float* Y = (float*)Yv + (size_t)grow * D_DIM;
                    Y[col0] = o0;
                    Y[col1] = o1;
                } else {
                    short* Y = (short*)Yv + (size_t)grow * D_DIM;
                    Y[col0] = f2bf(o0);
                    Y[col1] = f2bf(o1);
                }
            }
        }
    }
}

// ---------------- launch ----------------

extern "C" void kernel_launch(void* const* d_in, const int* in_sizes, int n_in,
                              void* d_out, int out_size, void* d_ws, size_t ws_size,
                              hipStream_t stream) {
    const float* x     = (const float*)d_in[0];
    const float* W     = (const float*)d_in[1];
    const float* bias  = (const float*)d_in[2];
    const float* gamma = (const float*)d_in[3];
    const float* beta  = (const float*)d_in[4];
    const int*   edges = (const int*)d_in[5];

    const int N = in_sizes[0] / D_DIM;
    const int E = in_sizes[5] / 2;
    const int L = in_sizes[1] / (D_DIM * D_DIM);

    const int* src = edges;
    const int* dst = edges + E;

    const int NB = (N + 1023) / 1024;

    // workspace carve — 16B alignment maintained
    char* w = (char*)d_ws;
    short* ActA = (short*)w; w += (size_t)N * D_DIM * sizeof(short);
    short* ActB = (short*)w; w += (size_t)N * D_DIM * sizeof(short);
    int* cnt     = (int*)w;  w += (size_t)((N + 3) & ~3) * sizeof(int);
    int* row_ptr = (int*)w;  w += (size_t)((N + 4) & ~3) * sizeof(int);
    int* cursor  = (int*)w;  w += (size_t)((N + 3) & ~3) * sizeof(int);
    int2* meta   = (int2*)w; w += (size_t)E * sizeof(int2);
    float* dinv  = (float*)w; w += (size_t)((N + 3) & ~3) * sizeof(float);
    int* partial = (int*)w;  w += (size_t)((NB + 3) & ~3) * sizeof(int);
    short* Wt    = (short*)w; w += (size_t)L * D_DIM * D_DIM * sizeof(short);

    // CSR build
    zero_cnt_kernel<<<(N + 255) / 256, 256, 0, stream>>>(cnt, N);
    count_kernel<<<(E + 255) / 256, 256, 0, stream>>>(dst, cnt, E);
    partial_kernel<<<NB, 256, 0, stream>>>(cnt, partial, N);
    scan_partials_kernel<<<1, 1024, 0, stream>>>(partial, NB, row_ptr, N, E);
    emit_kernel<<<NB, 256, 0, stream>>>(cnt, partial, row_ptr, cursor, dinv, N);
    fill_kernel<<<(E + 255) / 256, 256, 0, stream>>>(src, dst, dinv, cursor, meta, E);

    // W -> bf16 transpose (once per call)
    const int WT_TOTAL = L * D_DIM * D_DIM;
    wt_prep_kernel<<<(WT_TOTAL + 255) / 256, 256, 0, stream>>>(W, Wt, WT_TOTAL);

    const int GB = (N + 63) / 64;

    if (L == 1) {
        fused_layer_kernel<true, true><<<GB, 256, 0, stream>>>(x, Wt, row_ptr, meta, dinv,
                                                               bias, gamma, beta, d_out, N);
        return;
    }

    // layer 0: f32 x -> ActA (bf16)
    fused_layer_kernel<true, false><<<GB, 256, 0, stream>>>(x, Wt, row_ptr, meta, dinv,
                                                            bias, gamma, beta, ActA, N);
    const short* cur = ActA;
    for (int l = 1; l < L - 1; ++l) {
        short* nxt = (l & 1) ? ActB : ActA;
        fused_layer_kernel<false, false><<<GB, 256, 0, stream>>>(cur, Wt + (size_t)l * D_DIM * D_DIM,
                                                                 row_ptr, meta, dinv,
                                                                 bias + (size_t)l * D_DIM,
                                                                 gamma + (size_t)l * D_DIM,
                                                                 beta + (size_t)l * D_DIM, nxt, N);
        cur = nxt;
    }
    // final layer -> f32 d_out
    {
        const int l = L - 1;
        fused_layer_kernel<false, true><<<GB, 256, 0, stream>>>(cur, Wt + (size_t)l * D_DIM * D_DIM,
                                                                row_ptr, meta, dinv,
                                                                bias + (size_t)l * D_DIM,
                                                                gamma + (size_t)l * D_DIM,
                                                                beta + (size_t)l * D_DIM, d_out, N);
    }
}

// Round 10
// 367.555 us; speedup vs baseline: 1.9542x; 1.9542x over previous
//
#include <hip/hip_runtime.h>
#include <hip/hip_bf16.h>

#define D_DIM 128
#define AST 136   // padded LDS row stride (shorts) for the A tile
#define CST 132   // padded LDS row stride (shorts) for the C transpose

typedef __attribute__((ext_vector_type(8))) short short8v;
typedef __attribute__((ext_vector_type(4))) short short4v;
typedef __attribute__((ext_vector_type(4))) float floatx4;

__device__ __forceinline__ short f2bf(float x) {
    unsigned u = __builtin_bit_cast(unsigned, x);
    unsigned r = u + 0x7fff + ((u >> 16) & 1);   // RNE
    return (short)(r >> 16);
}
__device__ __forceinline__ float bflo(unsigned p) {
    return __builtin_bit_cast(float, p << 16);
}
__device__ __forceinline__ float bfhi(unsigned p) {
    return __builtin_bit_cast(float, p & 0xffff0000u);
}

// ---------------- CSR build ----------------

__global__ void zero_cnt_kernel(int* __restrict__ cnt, int n) {
    int i = blockIdx.x * blockDim.x + threadIdx.x;
    if (i < n) cnt[i] = 0;
}

__global__ void count_kernel(const int* __restrict__ dst, int* __restrict__ cnt, int e) {
    int i = blockIdx.x * blockDim.x + threadIdx.x;
    if (i < e) atomicAdd(&cnt[dst[i]], 1);
}

__global__ __launch_bounds__(256) void partial_kernel(const int* __restrict__ cnt,
                                                      int* __restrict__ partial, int n) {
    const int b = blockIdx.x, t = threadIdx.x;
    const int base = b * 1024 + t * 4;
    int s = 0;
    if (base + 3 < n) {
        int4 c = *(const int4*)(cnt + base);
        s = c.x + c.y + c.z + c.w;
    } else {
        for (int j = 0; j < 4; ++j) if (base + j < n) s += cnt[base + j];
    }
    #pragma unroll
    for (int m = 1; m < 64; m <<= 1) s += __shfl_xor(s, m, 64);
    __shared__ int ws[4];
    if ((t & 63) == 0) ws[t >> 6] = s;
    __syncthreads();
    if (t == 0) partial[b] = ws[0] + ws[1] + ws[2] + ws[3];
}

__global__ __launch_bounds__(1024) void scan_partials_kernel(int* __restrict__ partial, int nb,
                                                             int* __restrict__ row_ptr,
                                                             int n, int e) {
    __shared__ int sh[1024];
    const int t = threadIdx.x;
    sh[t] = (t < nb) ? partial[t] : 0;
    __syncthreads();
    for (int off = 1; off < 1024; off <<= 1) {
        int v = (t >= off) ? sh[t - off] : 0;
        __syncthreads();
        sh[t] += v;
        __syncthreads();
    }
    if (t < nb) partial[t] = (t == 0) ? 0 : sh[t - 1];
    if (t == 0) row_ptr[n] = e;
}

__global__ __launch_bounds__(256) void emit_kernel(const int* __restrict__ cnt,
                                                   const int* __restrict__ partial,
                                                   int* __restrict__ row_ptr,
                                                   int* __restrict__ cursor,
                                                   float* __restrict__ dinv, int n) {
    const int b = blockIdx.x, t = threadIdx.x;
    const int base = b * 1024 + t * 4;
    int4 c = make_int4(0, 0, 0, 0);
    if (base + 3 < n) {
        c = *(const int4*)(cnt + base);
    } else {
        if (base     < n) c.x = cnt[base];
        if (base + 1 < n) c.y = cnt[base + 1];
        if (base + 2 < n) c.z = cnt[base + 2];
        if (base + 3 < n) c.w = cnt[base + 3];
    }
    const int ts = c.x + c.y + c.z + c.w;
    int incl = ts;
    const int lane = t & 63;
    #pragma unroll
    for (int off = 1; off < 64; off <<= 1) {
        int v = __shfl_up(incl, off, 64);
        if (lane >= off) incl += v;
    }
    __shared__ int wsum[4];
    if (lane == 63) wsum[t >> 6] = incl;
    __syncthreads();
    const int w = t >> 6;
    int waveoff = 0;
    #pragma unroll
    for (int i = 0; i < 3; ++i) if (i < w) waveoff += wsum[i];
    const int basev = partial[b] + waveoff + (incl - ts);
    const int e0 = basev, e1 = e0 + c.x, e2 = e1 + c.y, e3 = e2 + c.z;
    if (base + 3 < n) {
        *(int4*)(row_ptr + base) = make_int4(e0, e1, e2, e3);
        *(int4*)(cursor  + base) = make_int4(e0, e1, e2, e3);
        *(float4*)(dinv + base) = make_float4(rsqrtf((float)(c.x + 1)), rsqrtf((float)(c.y + 1)),
                                              rsqrtf((float)(c.z + 1)), rsqrtf((float)(c.w + 1)));
    } else {
        int es[4] = {e0, e1, e2, e3};
        int cs[4] = {c.x, c.y, c.z, c.w};
        for (int j = 0; j < 4; ++j) if (base + j < n) {
            row_ptr[base + j] = es[j];
            cursor[base + j]  = es[j];
            dinv[base + j]    = rsqrtf((float)(cs[j] + 1));
        }
    }
}

// fill CSR with precomputed per-edge weight: meta = {src, dinv[src]*dinv[dst]}
__global__ void fill_kernel(const int* __restrict__ src, const int* __restrict__ dst,
                            const float* __restrict__ dinv,
                            int* __restrict__ cursor, int2* __restrict__ meta, int e) {
    int i = blockIdx.x * blockDim.x + threadIdx.x;
    if (i < e) {
        int s = src[i], d = dst[i];
        int p = atomicAdd(&cursor[d], 1);
        float w = dinv[s] * dinv[d];
        meta[p] = make_int2(s, __builtin_bit_cast(int, w));
    }
}

// ---------------- W transpose+convert: Wt[l][n][k] = bf16(W[l][k][n]) ----------------
__global__ __launch_bounds__(256) void wt_prep_kernel(const float* __restrict__ W,
                                                      short* __restrict__ Wt, int total) {
    int o = blockIdx.x * blockDim.x + threadIdx.x;
    if (o >= total) return;
    int l = o >> 14;
    int r = o & 16383;
    int nn = r >> 7;
    int k  = r & 127;
    Wt[o] = f2bf(W[(size_t)l * 16384 + (size_t)k * 128 + nn]);
}

// ---------------- GEMM: H(bf16) = act @ W, A via LDS + B in VGPRs ----------------
// Block = 256 = 4 waves, tile 64 rows x 128 cols. Wave w: cols [w*32, w*32+32).
// Epilogue: C transposed through LDS -> fully coalesced short8 (16B/lane) stores.
template <bool IN_F32>
__global__ __launch_bounds__(256) void gemm_mfma_kernel(const void* __restrict__ Xv,
                                                        const short* __restrict__ Wt,
                                                        short* __restrict__ H, int n) {
    __shared__ short Alds[64 * AST];   // reused for the C transpose (64*CST fits)
    const int t    = threadIdx.x;
    const int wv   = t >> 6;
    const int lane = t & 63;
    const int m    = lane & 15;
    const int quad = lane >> 4;
    const int row0 = blockIdx.x * 64;

    // B fragments (registers): col = (wv*2+c)*16 + m, k = kt*32 + quad*8
    short8v bfr[2][4];
    #pragma unroll
    for (int c = 0; c < 2; ++c) {
        const short* bp = Wt + (size_t)((wv * 2 + c) * 16 + m) * D_DIM + quad * 8;
        #pragma unroll
        for (int kt = 0; kt < 4; ++kt)
            bfr[c][kt] = *(const short8v*)(bp + kt * 32);
    }

    // stage A tile in LDS (coalesced bulk)
    if constexpr (IN_F32) {
        const float* X = (const float*)Xv;
        #pragma unroll
        for (int i = 0; i < 8; ++i) {
            int q  = t + i * 256;     // float4 id (2048)
            int r  = q >> 5;
            int k4 = q & 31;
            int row = row0 + r;
            float4 v = make_float4(0.f, 0.f, 0.f, 0.f);
            if (row < n) v = *(const float4*)(X + (size_t)row * D_DIM + k4 * 4);
            short4v s;
            s.x = f2bf(v.x); s.y = f2bf(v.y); s.z = f2bf(v.z); s.w = f2bf(v.w);
            *(short4v*)(&Alds[r * AST + k4 * 4]) = s;
        }
    } else {
        const short* X = (const short*)Xv;
        #pragma unroll
        for (int i = 0; i < 4; ++i) {
            int q  = t + i * 256;     // short8 id (1024)
            int r  = q >> 4;
            int kc = q & 15;
            int row = row0 + r;
            short8v v = {0,0,0,0,0,0,0,0};
            if (row < n) v = *(const short8v*)(X + (size_t)row * D_DIM + kc * 8);
            *(short8v*)(&Alds[r * AST + kc * 8]) = v;
        }
    }
    __syncthreads();

    floatx4 acc[4][2];
    #pragma unroll
    for (int rt = 0; rt < 4; ++rt) {
        const short* ab = &Alds[(rt * 16 + m) * AST + quad * 8];
        short8v afr[4];
        #pragma unroll
        for (int kt = 0; kt < 4; ++kt) afr[kt] = *(const short8v*)(ab + kt * 32);

        #pragma unroll
        for (int c = 0; c < 2; ++c) {
            floatx4 a = (floatx4){0.f, 0.f, 0.f, 0.f};
            #pragma unroll
            for (int kt = 0; kt < 4; ++kt)
                a = __builtin_amdgcn_mfma_f32_16x16x32_bf16(afr[kt], bfr[c][kt], a, 0, 0, 0);
            acc[rt][c] = a;
        }
    }
    __syncthreads();   // all A reads done; reuse LDS for C

    // C/D: col = (wv*2+c)*16 + m, row = rt*16 + quad*4 + r  -> LDS transpose
    #pragma unroll
    for (int rt = 0; rt < 4; ++rt) {
        #pragma unroll
        for (int c = 0; c < 2; ++c) {
            const int col = (wv * 2 + c) * 16 + m;
            #pragma unroll
            for (int r = 0; r < 4; ++r)
                Alds[(rt * 16 + quad * 4 + r) * CST + col] = f2bf(acc[rt][c][r]);
        }
    }
    __syncthreads();

    // coalesced stores: 16 lanes cover a full 256B row
    #pragma unroll
    for (int i = 0; i < 4; ++i) {
        int q  = t + i * 256;     // short8 id (1024)
        int r  = q >> 4;
        int kc = q & 15;
        int row = row0 + r;
        if (row < n)
            *(short8v*)(H + (size_t)row * D_DIM + kc * 8) = *(const short8v*)(&Alds[r * CST + kc * 8]);
    }
}

// ---------------- Aggregation + bias + ReLU + LayerNorm ----------------
// One wave per TWO consecutive nodes, gathers interleaved (4+4 in flight);
// scalar metadata (wave-uniform) in SGPRs; per-node LN epilogue.
template <bool OUT_BF16>
__global__ __launch_bounds__(256) void agg_kernel(const short* __restrict__ Hb,
                                                  const int* __restrict__ row_ptr,
                                                  const int2* __restrict__ meta,
                                                  const float* __restrict__ dinv,
                                                  const float* __restrict__ bias,
                                                  const float* __restrict__ gamma,
                                                  const float* __restrict__ beta,
                                                  void* __restrict__ Yv, int n) {
    const int wave = __builtin_amdgcn_readfirstlane(threadIdx.x >> 6);
    const int lane = threadIdx.x & 63;
    const int vA = (blockIdx.x * 4 + wave) * 2;
    if (vA >= n) return;
    const bool hasB = (vA + 1) < n;
    const int vB = hasB ? vA + 1 : vA;

    const float dvA = dinv[vA];
    const float dvB = dinv[vB];
    const int begA = row_ptr[vA];
    const int endA = row_ptr[vA + 1];
    const int begB = row_ptr[vB];
    const int endB = row_ptr[vB + 1];
    const int cntA = endA - begA;
    const int cntB = hasB ? (endB - begB) : 0;
    const int mx = cntA > cntB ? cntA : cntB;

    // self loops (2 independent loads)
    const unsigned psA = ((const unsigned*)(Hb + (size_t)vA * D_DIM))[lane];
    const unsigned psB = ((const unsigned*)(Hb + (size_t)vB * D_DIM))[lane];
    float axA = bflo(psA) * (dvA * dvA);
    float ayA = bfhi(psA) * (dvA * dvA);
    float axB = bflo(psB) * (dvB * dvB);
    float ayB = bfhi(psB) * (dvB * dvB);

    for (int k = 0; k < mx; k += 4) {
        int   idx[8];
        float wgt[8];
        #pragma unroll
        for (int j = 0; j < 4; ++j) {
            int ii = min(begA + k + j, endA - 1); ii = max(ii, 0);
            const int2 mm = meta[ii];
            idx[j] = mm.x;
            wgt[j] = (k + j < cntA) ? __builtin_bit_cast(float, mm.y) : 0.f;
        }
        #pragma unroll
        for (int j = 0; j < 4; ++j) {
            int ii = min(begB + k + j, endB - 1); ii = max(ii, 0);
            const int2 mm = meta[ii];
            idx[4 + j] = mm.x;
            wgt[4 + j] = (k + j < cntB) ? __builtin_bit_cast(float, mm.y) : 0.f;
        }
        unsigned p[8];
        #pragma unroll
        for (int j = 0; j < 8; ++j)
            p[j] = ((const unsigned*)(Hb + (size_t)idx[j] * D_DIM))[lane];
        #pragma unroll
        for (int j = 0; j < 4; ++j) {
            axA = fmaf(wgt[j], bflo(p[j]), axA);
            ayA = fmaf(wgt[j], bfhi(p[j]), ayA);
            axB = fmaf(wgt[4 + j], bflo(p[4 + j]), axB);
            ayB = fmaf(wgt[4 + j], bfhi(p[4 + j]), ayB);
        }
    }

    const float2 bb = ((const float2*)bias)[lane];
    const float2 gg = ((const float2*)gamma)[lane];
    const float2 be = ((const float2*)beta)[lane];

    #pragma unroll
    for (int s = 0; s < 2; ++s) {
        if (s == 1 && !hasB) break;
        float a0 = fmaxf((s ? axB : axA) + bb.x, 0.f);
        float a1 = fmaxf((s ? ayB : ayA) + bb.y, 0.f);
        float s1 = a0 + a1;
        float s2 = a0 * a0 + a1 * a1;
        #pragma unroll
        for (int m = 1; m < 64; m <<= 1) {
            s1 += __shfl_xor(s1, m, 64);
            s2 += __shfl_xor(s2, m, 64);
        }
        const float mu  = s1 * (1.f / 128.f);
        const float var = s2 * (1.f / 128.f) - mu * mu;
        const float rs  = rsqrtf(var + 1e-5f);
        const float o0 = (a0 - mu) * rs * gg.x + be.x;
        const float o1 = (a1 - mu) * rs * gg.y + be.y;
        const int v = s ? vB : vA;
        if constexpr (OUT_BF16) {
            unsigned pack = (unsigned)(unsigned short)f2bf(o0) |
                            ((unsigned)(unsigned short)f2bf(o1) << 16);
            ((unsigned*)((short*)Yv + (size_t)v * D_DIM))[lane] = pack;
        } else {
            float2 o; o.x = o0; o.y = o1;
            ((float2*)((float*)Yv + (size_t)v * D_DIM))[lane] = o;
        }
    }
}

// ---------------- launch ----------------

extern "C" void kernel_launch(void* const* d_in, const int* in_sizes, int n_in,
                              void* d_out, int out_size, void* d_ws, size_t ws_size,
                              hipStream_t stream) {
    const float* x     = (const float*)d_in[0];
    const float* W     = (const float*)d_in[1];
    const float* bias  = (const float*)d_in[2];
    const float* gamma = (const float*)d_in[3];
    const float* beta  = (const float*)d_in[4];
    const int*   edges = (const int*)d_in[5];

    const int N = in_sizes[0] / D_DIM;
    const int E = in_sizes[5] / 2;
    const int L = in_sizes[1] / (D_DIM * D_DIM);

    const int* src = edges;
    const int* dst = edges + E;

    const int NB = (N + 1023) / 1024;

    // workspace carve — 16B alignment maintained
    char* w = (char*)d_ws;
    short* Hb   = (short*)w; w += (size_t)N * D_DIM * sizeof(short);
    short* Act  = (short*)w; w += (size_t)N * D_DIM * sizeof(short);
    int* cnt     = (int*)w;  w += (size_t)((N + 3) & ~3) * sizeof(int);
    int* row_ptr = (int*)w;  w += (size_t)((N + 4) & ~3) * sizeof(int);
    int* cursor  = (int*)w;  w += (size_t)((N + 3) & ~3) * sizeof(int);
    int2* meta   = (int2*)w; w += (size_t)E * sizeof(int2);
    float* dinv  = (float*)w; w += (size_t)((N + 3) & ~3) * sizeof(float);
    int* partial = (int*)w;  w += (size_t)((NB + 3) & ~3) * sizeof(int);
    short* Wt    = (short*)w; w += (size_t)L * D_DIM * D_DIM * sizeof(short);

    // CSR build
    zero_cnt_kernel<<<(N + 255) / 256, 256, 0, stream>>>(cnt, N);
    count_kernel<<<(E + 255) / 256, 256, 0, stream>>>(dst, cnt, E);
    partial_kernel<<<NB, 256, 0, stream>>>(cnt, partial, N);
    scan_partials_kernel<<<1, 1024, 0, stream>>>(partial, NB, row_ptr, N, E);
    emit_kernel<<<NB, 256, 0, stream>>>(cnt, partial, row_ptr, cursor, dinv, N);
    fill_kernel<<<(E + 255) / 256, 256, 0, stream>>>(src, dst, dinv, cursor, meta, E);

    // W -> bf16 transpose (once per call)
    const int WT_TOTAL = L * D_DIM * D_DIM;
    wt_prep_kernel<<<(WT_TOTAL + 255) / 256, 256, 0, stream>>>(W, Wt, WT_TOTAL);

    const int GB = (N + 63) / 64;
    const int AB = (N + 7) / 8;   // 4 waves/block x 2 nodes/wave

    // layer 0: f32 x -> H(bf16) -> Act(bf16)
    gemm_mfma_kernel<true><<<GB, 256, 0, stream>>>(x, Wt, Hb, N);
    agg_kernel<true><<<AB, 256, 0, stream>>>(Hb, row_ptr, meta, dinv,
                                             bias, gamma, beta, Act, N);
    // layers 1..L-2: bf16 -> bf16
    for (int l = 1; l < L - 1; ++l) {
        gemm_mfma_kernel<false><<<GB, 256, 0, stream>>>(Act, Wt + (size_t)l * D_DIM * D_DIM, Hb, N);
        agg_kernel<true><<<AB, 256, 0, stream>>>(Hb, row_ptr, meta, dinv,
                                                 bias + (size_t)l * D_DIM,
                                                 gamma + (size_t)l * D_DIM,
                                                 beta + (size_t)l * D_DIM, Act, N);
    }
    // final layer: bf16 -> f32 d_out
    {
        int l = L - 1;
        gemm_mfma_kernel<false><<<GB, 256, 0, stream>>>(Act, Wt + (size_t)l * D_DIM * D_DIM, Hb, N);
        agg_kernel<false><<<AB, 256, 0, stream>>>(Hb, row_ptr, meta, dinv,
                                                  bias + (size_t)l * D_DIM,
                                                  gamma + (size_t)l * D_DIM,
                                                  beta + (size_t)l * D_DIM, d_out, N);
    }
}